// Round 1
// baseline (904.053 us; speedup 1.0000x reference)
//
#include <hip/hip_runtime.h>

// Problem constants
constexpr int cB    = 16;
constexpr int cCIN  = 96;
constexpr int cCOUT = 192;
constexpr int cNIN  = 16384;
constexpr int cNOUT = 4096;
constexpr int cK    = 16;
constexpr int cM    = 5;   // harmonics
constexpr int cME   = 6;   // extended (5 harm + 1 pool col)
constexpr float cEPS = 1e-5f;

// Tiling
constexpr int TN = 32;   // n-points per block
constexpr int CC = 4;    // channels per chunk

// ---------------- weight prepack: wpack[c][m'][o] ----------------
__global__ void k_pack(const float* __restrict__ conv_w,
                       const float* __restrict__ pool_w,
                       float* __restrict__ wpack) {
    int i = blockIdx.x * 256 + threadIdx.x;
    if (i >= cCIN * cME * cCOUT) return;
    int c = i / (cME * cCOUT);
    int r = i % (cME * cCOUT);
    int m = r / cCOUT;
    int o = r % cCOUT;
    float v = (m < cM) ? conv_w[(o * cCIN + c) * cM + m] : pool_w[o * cCIN + c];
    wpack[i] = v;
}

// ---------------- fused gather + feat + GEMM ----------------
// grid: (NOUT/TN, B), block: 256
// outputs: conv_raw -> ws, identity -> d_out (pre-BN staging)
__launch_bounds__(256)
__global__ void k_main(const float* __restrict__ x,
                       const int* __restrict__ idx,
                       const float* __restrict__ basis,
                       const float* __restrict__ wpack,
                       const float* __restrict__ pool_b,
                       float* __restrict__ conv_out,
                       float* __restrict__ ident_out) {
    __shared__ int   s_idx[TN * cK];                 // 512 ints
    __shared__ float s_basis[TN * cME * cK];         // [nl][m'][k], 3072 f
    __shared__ __align__(16) float s_pool[CC*TN*cK + CC*cME*TN + CC*cME*cCOUT]; // 7424 f
    float* s_neigh = s_pool;                          // [cc][nl][k]  2048
    float* s_feat  = s_pool + CC*TN*cK;               // [cc][m'][nl] 768
    float* s_w     = s_pool + CC*TN*cK + CC*cME*TN;   // [cc][m'][o]  4608
    float* s_out   = s_pool;                          // alias, 192*33=6336 <= 7424

    const int t  = threadIdx.x;
    const int b  = blockIdx.y;
    const int n0 = blockIdx.x * TN;

    // stage idx
    for (int i = t; i < TN * cK; i += 256)
        s_idx[i] = idx[n0 * cK + i];
    // stage basis -> [nl][m'][k]; source basis[(n0+nl)*80 + k*5 + m]
    for (int i = t; i < TN * cM * cK; i += 256) {
        int nl = i / (cM * cK);
        int r  = i % (cM * cK);
        int m  = r / cK;
        int k  = r % cK;
        s_basis[(nl * cME + m) * cK + k] = basis[(n0 + nl) * (cK * cM) + k * cM + m];
    }
    for (int i = t; i < TN * cK; i += 256) {
        int nl = i / cK, k = i % cK;
        s_basis[(nl * cME + 5) * cK + k] = 1.0f / cK;   // mean-pool column
    }
    __syncthreads();

    const int og = t & 15;       // 16 o-groups of 12
    const int ng = t >> 4;       // 16 n-groups of 2
    const int obase = og * 12;
    const int nbase = ng * 2;

    float accC[2][12];
    float accI[2][12];
#pragma unroll
    for (int i = 0; i < 2; ++i)
#pragma unroll
        for (int j = 0; j < 12; ++j) { accC[i][j] = 0.f; accI[i][j] = 0.f; }

    const float* xb = x + (size_t)b * cCIN * cNIN;

    for (int c0 = 0; c0 < cCIN; c0 += CC) {
        // gather x into s_neigh
        for (int r = t; r < CC * TN * cK; r += 256) {
            int cc  = r >> 9;        // / (TN*cK)=512
            int rem = r & 511;
            s_neigh[r] = xb[(size_t)(c0 + cc) * cNIN + s_idx[rem]];
        }
        // stage weights (contiguous chunk of wpack)
        {
            const float4* src = (const float4*)(wpack + c0 * (cME * cCOUT));
            float4* dst = (float4*)s_w;
            for (int r = t; r < CC * cME * cCOUT / 4; r += 256)
                dst[r] = src[r];
        }
        __syncthreads();

        // feat: [cc][m'][nl], 768 values
        for (int r = t; r < CC * cME * TN; r += 256) {
            int cc  = r / (cME * TN);
            int rem = r % (cME * TN);
            int m   = rem / TN;
            int nl  = rem % TN;
            const float* nb = &s_neigh[(cc * TN + nl) * cK];
            const float* bb = &s_basis[(nl * cME + m) * cK];
            float s = 0.f;
#pragma unroll
            for (int k = 0; k < cK; ++k) s = fmaf(nb[k], bb[k], s);
            s_feat[r] = s;
        }
        __syncthreads();

        // accumulate GEMM tile
#pragma unroll
        for (int cc = 0; cc < CC; ++cc) {
#pragma unroll
            for (int m = 0; m < cME; ++m) {
                const float* fp = &s_feat[(cc * cME + m) * TN + nbase];
                float f0 = fp[0], f1 = fp[1];
                const float* wp = &s_w[(cc * cME + m) * cCOUT + obase];
                if (m < 5) {
#pragma unroll
                    for (int j = 0; j < 12; ++j) {
                        float w = wp[j];
                        accC[0][j] = fmaf(f0, w, accC[0][j]);
                        accC[1][j] = fmaf(f1, w, accC[1][j]);
                    }
                } else {
#pragma unroll
                    for (int j = 0; j < 12; ++j) {
                        float w = wp[j];
                        accI[0][j] = fmaf(f0, w, accI[0][j]);
                        accI[1][j] = fmaf(f1, w, accI[1][j]);
                    }
                }
            }
        }
        __syncthreads();
    }

    // ---- epilogue: stage through LDS (stride-33 pad) for coalesced writes ----
    float pb[12];
#pragma unroll
    for (int j = 0; j < 12; ++j) pb[j] = pool_b[obase + j];

    // conv
#pragma unroll
    for (int i = 0; i < 2; ++i)
#pragma unroll
        for (int j = 0; j < 12; ++j)
            s_out[(obase + j) * 33 + nbase + i] = accC[i][j];
    __syncthreads();
    for (int r = t; r < cCOUT * TN; r += 256) {
        int o = r >> 5, nl = r & 31;
        conv_out[((size_t)b * cCOUT + o) * cNOUT + n0 + nl] = s_out[o * 33 + nl];
    }
    __syncthreads();
    // identity (+ pool_b)
#pragma unroll
    for (int i = 0; i < 2; ++i)
#pragma unroll
        for (int j = 0; j < 12; ++j)
            s_out[(obase + j) * 33 + nbase + i] = accI[i][j] + pb[j];
    __syncthreads();
    for (int r = t; r < cCOUT * TN; r += 256) {
        int o = r >> 5, nl = r & 31;
        ident_out[((size_t)b * cCOUT + o) * cNOUT + n0 + nl] = s_out[o * 33 + nl];
    }
}

// ---------------- per-channel BN stats -> scale/shift ----------------
__global__ void k_stats(const float* __restrict__ conv,
                        const float* __restrict__ gamma,
                        const float* __restrict__ beta,
                        float* __restrict__ ss) {
    int o = blockIdx.x, t = threadIdx.x;
    float s1 = 0.f, s2 = 0.f;
    for (int b = 0; b < cB; ++b) {
        const float* p = conv + ((size_t)b * cCOUT + o) * cNOUT;
        for (int n = t; n < cNOUT; n += 256) {
            float v = p[n];
            s1 += v;
            s2 = fmaf(v, v, s2);
        }
    }
#pragma unroll
    for (int off = 32; off; off >>= 1) {
        s1 += __shfl_down(s1, off);
        s2 += __shfl_down(s2, off);
    }
    __shared__ float w1[4], w2[4];
    int lane = t & 63, wid = t >> 6;
    if (lane == 0) { w1[wid] = s1; w2[wid] = s2; }
    __syncthreads();
    if (t == 0) {
        float S1 = w1[0] + w1[1] + w1[2] + w1[3];
        float S2 = w2[0] + w2[1] + w2[2] + w2[3];
        float inv  = 1.0f / (cB * cNOUT);
        float mean = S1 * inv;
        float var  = S2 * inv - mean * mean;
        float scale = gamma[o] * rsqrtf(var + cEPS);
        ss[o]         = scale;
        ss[cCOUT + o] = beta[o] - mean * scale;
    }
}

// ---------------- BN apply + residual ----------------
__global__ void k_final(const float* __restrict__ conv,
                        const float* __restrict__ ss,
                        float* __restrict__ out) {
    size_t i = ((size_t)blockIdx.x * 256 + threadIdx.x) * 4;
    int o = (int)((i >> 12) % cCOUT);   // (i / 4096) % 192
    float4 c = *(const float4*)(conv + i);
    float4 d = *(const float4*)(out + i);   // identity written by k_main
    float sc = ss[o], sh = ss[cCOUT + o];
    float4 r;
    r.x = fmaf(c.x, sc, sh + d.x);
    r.y = fmaf(c.y, sc, sh + d.y);
    r.z = fmaf(c.z, sc, sh + d.z);
    r.w = fmaf(c.w, sc, sh + d.w);
    *(float4*)(out + i) = r;
}

extern "C" void kernel_launch(void* const* d_in, const int* in_sizes, int n_in,
                              void* d_out, int out_size, void* d_ws, size_t ws_size,
                              hipStream_t stream) {
    const float* x      = (const float*)d_in[0];
    const int*   idx    = (const int*)d_in[1];
    const float* basis  = (const float*)d_in[2];
    const float* conv_w = (const float*)d_in[3];
    // d_in[4] = conv_b: cancels exactly under BN (and is zeros) -> unused
    const float* pool_w = (const float*)d_in[5];
    const float* pool_b = (const float*)d_in[6];
    const float* gamma  = (const float*)d_in[7];
    const float* beta   = (const float*)d_in[8];
    float* out = (float*)d_out;

    float* conv_ws = (float*)d_ws;                               // 12582912 f
    float* ss      = conv_ws + (size_t)cB * cCOUT * cNOUT;       // 384 f
    float* wpack   = ss + 2 * cCOUT;                             // 110592 f

    k_pack<<<(cCIN * cME * cCOUT + 255) / 256, 256, 0, stream>>>(conv_w, pool_w, wpack);
    k_main<<<dim3(cNOUT / TN, cB), 256, 0, stream>>>(x, idx, basis, wpack, pool_b,
                                                     conv_ws, out);
    k_stats<<<cCOUT, 256, 0, stream>>>(conv_ws, gamma, beta, ss);
    k_final<<<(size_t)cB * cCOUT * cNOUT / 1024, 256, 0, stream>>>(conv_ws, ss, out);
}

// Round 2
// 249.884 us; speedup vs baseline: 3.6179x; 3.6179x over previous
//
#include <hip/hip_runtime.h>

typedef __attribute__((ext_vector_type(8))) short s16x8;
typedef __attribute__((ext_vector_type(4))) float f32x4;

constexpr int cB = 16, cCIN = 96, cCOUT = 192, cNIN = 16384, cNOUT = 4096, cK = 16;
constexpr float cEPS = 1e-5f;

// ws layout (bytes)
constexpr size_t OFF_XT    = 0;           // bf16 xt[b][j][c]     50,331,648 B (aliased by conv later)
constexpr size_t OFF_FEATA = 50331648;    // bf16 frag-order feat 75,497,472 B
constexpr size_t OFF_CONV  = 0;           // fp32 conv[b][o][n]   50,331,648 B (alias of XT; XT dead by then)
constexpr size_t OFF_WB    = 125829120;   // bf16 frag-order W       221,184 B
constexpr size_t OFF_SS    = 126050304;   // fp32 scale/shift          1,536 B

__device__ inline unsigned bf16_rne(float f) {
    unsigned u = __builtin_bit_cast(unsigned, f);
    return (u + 0x7fffu + ((u >> 16) & 1u)) >> 16;
}
__device__ inline float bf16_f(unsigned short h) {
    unsigned u = ((unsigned)h) << 16;
    return __builtin_bit_cast(float, u);
}

// ---------- K1: transpose x[b][c][j] fp32 -> xt[b][j][c] bf16 ----------
__launch_bounds__(256)
__global__ void k_tr(const float* __restrict__ x, unsigned* __restrict__ xto) {
    __shared__ float s[96 * 133];
    const int b = blockIdx.y, j0 = blockIdx.x * 128, t = threadIdx.x;
    const float* xb = x + (size_t)b * 96 * 16384 + j0;
    for (int q = t; q < 3072; q += 256) {
        int c = q >> 5, j4 = (q & 31) * 4;
        float4 v = *(const float4*)(xb + (size_t)c * 16384 + j4);
        s[c * 133 + j4 + 0] = v.x;
        s[c * 133 + j4 + 1] = v.y;
        s[c * 133 + j4 + 2] = v.z;
        s[c * 133 + j4 + 3] = v.w;
    }
    __syncthreads();
    for (int q = t; q < 6144; q += 256) {
        int cp = q % 48, jj = q / 48;
        float f0 = s[(2 * cp) * 133 + jj];
        float f1 = s[(2 * cp + 1) * 133 + jj];
        unsigned pr = bf16_rne(f0) | (bf16_rne(f1) << 16);
        xto[(size_t)(b * 16384 + j0 + jj) * 48 + cp] = pr;
    }
}

// ---------- K1b: pack weights into B-fragment order ----------
// wB[((ot*18 + s)*64 + lane)*8 + r] = W[ko][o], o = ot*16+(lane&15), ko = s*32+(lane>>4)*8+r
// ko order: m*96+c for m<5 (conv), 480+c (pool)
__global__ void k_pack(const float* __restrict__ cw, const float* __restrict__ pw,
                       unsigned short* __restrict__ wB) {
    int e = blockIdx.x * 256 + threadIdx.x;
    if (e >= 110592) return;
    int r = e & 7, l = (e >> 3) & 63;
    int ts = e >> 9;               // ot*18 + s
    int s = ts % 18, ot = ts / 18;
    int o = ot * 16 + (l & 15);
    int ko = s * 32 + ((l >> 4) << 3) + r;
    float v;
    if (ko < 480) { int m = ko / 96, c = ko % 96; v = cw[(o * 96 + c) * 5 + m]; }
    else          { int c = ko - 480;             v = pw[o * 96 + c]; }
    wB[e] = (unsigned short)bf16_rne(v);
}

// ---------- K2: gather + feat -> featA in A-fragment order ----------
// block: 16 n-points (one 16-row tile) for one b; 256 threads
__launch_bounds__(256)
__global__ void k_feat(const unsigned short* __restrict__ xt,
                       const int* __restrict__ idx,
                       const float* __restrict__ basis,
                       unsigned short* __restrict__ featA) {
    __shared__ unsigned short g[256 * 104];   // [kk*16+nl][c], 208B rows
    __shared__ float s_bas[16 * 97];          // [nl][k*6+m]
    __shared__ int s_idx[256];                // [nl*16+kk]
    const int t = threadIdx.x, b = blockIdx.y, n0 = blockIdx.x * 16;

    s_idx[t] = idx[n0 * 16 + t];
    for (int i = t; i < 16 * 96; i += 256) {
        int nl = i / 96, km = i % 96, k = km / 6, m = km % 6;
        float v = (m < 5) ? basis[((size_t)(n0 + nl) * 16 + k) * 5 + m] : 0.0625f;
        s_bas[nl * 97 + km] = v;
    }
    __syncthreads();

    for (int q = t; q < 3072; q += 256) {
        int row = q / 12, c16 = q % 12;
        int nl = row & 15, kk = row >> 4;
        int j = s_idx[nl * 16 + kk];
        const uint4* src = (const uint4*)(xt + (size_t)(b * 16384 + j) * 96 + c16 * 8);
        *(uint4*)(&g[row * 104 + c16 * 8]) = *src;
    }
    __syncthreads();

    if (t < 192) {
        const int c8 = t >> 4, nl = t & 15;
        float fm[6][8];
#pragma unroll
        for (int m = 0; m < 6; ++m)
#pragma unroll
            for (int j = 0; j < 8; ++j) fm[m][j] = 0.f;

        for (int k = 0; k < 16; ++k) {
            s16x8 v = *(const s16x8*)(&g[(k * 16 + nl) * 104 + c8 * 8]);
            float gf[8];
#pragma unroll
            for (int j = 0; j < 8; ++j) gf[j] = bf16_f((unsigned short)v[j]);
#pragma unroll
            for (int m = 0; m < 6; ++m) {
                float bv = s_bas[nl * 97 + k * 6 + m];
#pragma unroll
                for (int j = 0; j < 8; ++j) fm[m][j] = fmaf(gf[j], bv, fm[m][j]);
            }
        }
        const int tile = b * 256 + blockIdx.x;
        const int fl = nl + ((c8 & 3) << 4);
#pragma unroll
        for (int m = 0; m < 6; ++m) {
            int s = 3 * m + (c8 >> 2);
            uint4 o;
            o.x = bf16_rne(fm[m][0]) | (bf16_rne(fm[m][1]) << 16);
            o.y = bf16_rne(fm[m][2]) | (bf16_rne(fm[m][3]) << 16);
            o.z = bf16_rne(fm[m][4]) | (bf16_rne(fm[m][5]) << 16);
            o.w = bf16_rne(fm[m][6]) | (bf16_rne(fm[m][7]) << 16);
            *(uint4*)(featA + ((size_t)(tile * 18 + s) * 64 + fl) * 8) = o;
        }
    }
}

// ---------- K3: GEMM via MFMA, frag-order global loads, no LDS ----------
// block: 64 rows x 192 cols; 4 waves = 2 row x 2 col; wave: 32 rows x 96 cols
__launch_bounds__(256)
__global__ void k_gemm(const unsigned short* __restrict__ featA,
                       const unsigned short* __restrict__ wB,
                       float* __restrict__ conv, float* __restrict__ outI) {
    const int t = threadIdx.x;
    const int w = t >> 6, lane = t & 63;
    const int wr = w & 1, wc = w >> 1;
    const int tile0 = blockIdx.x * 4 + wr * 2;
    const s16x8* A  = (const s16x8*)featA;
    const s16x8* Bw = (const s16x8*)wB;

    f32x4 accC[2][6], accI[2][6];
    const f32x4 z = {0.f, 0.f, 0.f, 0.f};
#pragma unroll
    for (int rt = 0; rt < 2; ++rt)
#pragma unroll
        for (int j = 0; j < 6; ++j) { accC[rt][j] = z; accI[rt][j] = z; }

    for (int s = 0; s < 15; ++s) {
        s16x8 a0 = A[(size_t)(tile0 * 18 + s) * 64 + lane];
        s16x8 a1 = A[(size_t)((tile0 + 1) * 18 + s) * 64 + lane];
#pragma unroll
        for (int j = 0; j < 6; ++j) {
            s16x8 bf = Bw[(size_t)((wc * 6 + j) * 18 + s) * 64 + lane];
            accC[0][j] = __builtin_amdgcn_mfma_f32_16x16x32_bf16(a0, bf, accC[0][j], 0, 0, 0);
            accC[1][j] = __builtin_amdgcn_mfma_f32_16x16x32_bf16(a1, bf, accC[1][j], 0, 0, 0);
        }
    }
#pragma unroll
    for (int s = 15; s < 18; ++s) {
        s16x8 a0 = A[(size_t)(tile0 * 18 + s) * 64 + lane];
        s16x8 a1 = A[(size_t)((tile0 + 1) * 18 + s) * 64 + lane];
#pragma unroll
        for (int j = 0; j < 6; ++j) {
            s16x8 bf = Bw[(size_t)((wc * 6 + j) * 18 + s) * 64 + lane];
            accI[0][j] = __builtin_amdgcn_mfma_f32_16x16x32_bf16(a0, bf, accI[0][j], 0, 0, 0);
            accI[1][j] = __builtin_amdgcn_mfma_f32_16x16x32_bf16(a1, bf, accI[1][j], 0, 0, 0);
        }
    }

    const int col_l = lane & 15, rg = (lane >> 4) * 4;
#pragma unroll
    for (int rt = 0; rt < 2; ++rt) {
        int rowb = (tile0 + rt) * 16 + rg;
#pragma unroll
        for (int j = 0; j < 6; ++j) {
            int o = (wc * 6 + j) * 16 + col_l;
#pragma unroll
            for (int r = 0; r < 4; ++r) {
                int row = rowb + r;
                int b = row >> 12, n = row & 4095;
                size_t oidx = ((size_t)(b * 192 + o)) * 4096 + n;
                conv[oidx] = accC[rt][j][r];
                outI[oidx] = accI[rt][j][r];
            }
        }
    }
}

// ---------- K4: per-channel BN stats -> scale/shift (shift includes pool_b) ----------
__global__ void k_stats(const float* __restrict__ conv,
                        const float* __restrict__ gamma,
                        const float* __restrict__ beta,
                        const float* __restrict__ pool_b,
                        float* __restrict__ ss) {
    int o = blockIdx.x, t = threadIdx.x;
    float s1 = 0.f, s2 = 0.f;
    for (int b = 0; b < cB; ++b) {
        const float* p = conv + ((size_t)b * cCOUT + o) * cNOUT;
        for (int n = t; n < cNOUT; n += 256) {
            float v = p[n];
            s1 += v;
            s2 = fmaf(v, v, s2);
        }
    }
#pragma unroll
    for (int off = 32; off; off >>= 1) {
        s1 += __shfl_down(s1, off);
        s2 += __shfl_down(s2, off);
    }
    __shared__ float w1[4], w2[4];
    int lane = t & 63, wid = t >> 6;
    if (lane == 0) { w1[wid] = s1; w2[wid] = s2; }
    __syncthreads();
    if (t == 0) {
        float S1 = w1[0] + w1[1] + w1[2] + w1[3];
        float S2 = w2[0] + w2[1] + w2[2] + w2[3];
        float inv  = 1.0f / (cB * cNOUT);
        float mean = S1 * inv;
        float var  = S2 * inv - mean * mean;
        float scale = gamma[o] * rsqrtf(var + cEPS);
        ss[o]         = scale;
        ss[cCOUT + o] = beta[o] - mean * scale + pool_b[o];
    }
}

// ---------- K5: BN apply + residual ----------
__global__ void k_final(const float* __restrict__ conv,
                        const float* __restrict__ ss,
                        float* __restrict__ out) {
    size_t i = ((size_t)blockIdx.x * 256 + threadIdx.x) * 4;
    int o = (int)((i >> 12) % cCOUT);
    float4 c = *(const float4*)(conv + i);
    float4 d = *(const float4*)(out + i);   // identity written by k_gemm
    float sc = ss[o], sh = ss[cCOUT + o];
    float4 r;
    r.x = fmaf(c.x, sc, sh + d.x);
    r.y = fmaf(c.y, sc, sh + d.y);
    r.z = fmaf(c.z, sc, sh + d.z);
    r.w = fmaf(c.w, sc, sh + d.w);
    *(float4*)(out + i) = r;
}

extern "C" void kernel_launch(void* const* d_in, const int* in_sizes, int n_in,
                              void* d_out, int out_size, void* d_ws, size_t ws_size,
                              hipStream_t stream) {
    const float* x      = (const float*)d_in[0];
    const int*   idx    = (const int*)d_in[1];
    const float* basis  = (const float*)d_in[2];
    const float* conv_w = (const float*)d_in[3];
    // d_in[4] = conv_b: cancels exactly under BN -> unused
    const float* pool_w = (const float*)d_in[5];
    const float* pool_b = (const float*)d_in[6];
    const float* gamma  = (const float*)d_in[7];
    const float* beta   = (const float*)d_in[8];
    float* out = (float*)d_out;

    char* wsb = (char*)d_ws;
    unsigned short* xt    = (unsigned short*)(wsb + OFF_XT);
    unsigned short* featA = (unsigned short*)(wsb + OFF_FEATA);
    float*          conv  = (float*)(wsb + OFF_CONV);   // aliases xt (xt dead by k_gemm)
    unsigned short* wB    = (unsigned short*)(wsb + OFF_WB);
    float*          ss    = (float*)(wsb + OFF_SS);

    k_tr  <<<dim3(cNIN / 128, cB), 256, 0, stream>>>(x, (unsigned*)xt);
    k_pack<<<(110592 + 255) / 256, 256, 0, stream>>>(conv_w, pool_w, wB);
    k_feat<<<dim3(cNOUT / 16, cB), 256, 0, stream>>>(xt, idx, basis, featA);
    k_gemm<<<(cB * cNOUT) / 64, 256, 0, stream>>>(featA, wB, conv, out);
    k_stats<<<cCOUT, 256, 0, stream>>>(conv, gamma, beta, pool_b, ss);
    k_final<<<(size_t)cB * cCOUT * cNOUT / 1024, 256, 0, stream>>>(conv, ss, out);
}

// Round 3
// 150.174 us; speedup vs baseline: 6.0200x; 1.6640x over previous
//
#include <hip/hip_runtime.h>

typedef __attribute__((ext_vector_type(8))) short s16x8;
typedef __attribute__((ext_vector_type(4))) float f32x4;

constexpr int cB = 16, cCIN = 96, cCOUT = 192, cNIN = 16384, cNOUT = 4096, cK = 16;
constexpr float cEPS = 1e-5f;

// ws layout (bytes)
constexpr size_t OFF_XT     = 0;           // bf16 xt[b][j][c]  50,331,648 B (dead after k_feat)
constexpr size_t OFF_CONVB  = 0;           // bf16 conv[b][o][n] 25,165,824 B (aliases xt)
constexpr size_t OFF_IDENTB = 25165824;    // bf16 ident[b][o][n] 25,165,824 B (aliases xt)
constexpr size_t OFF_FEATA  = 50331648;    // bf16 frag-order feat 75,497,472 B
constexpr size_t OFF_WB     = 125829120;   // bf16 frag-order W 221,184 B
constexpr size_t OFF_SS     = 126050304;   // fp32 scale/shift 1,536 B

__device__ inline unsigned bf16_rne(float f) {
    unsigned u = __builtin_bit_cast(unsigned, f);
    return (u + 0x7fffu + ((u >> 16) & 1u)) >> 16;
}
__device__ inline float bf16_f(unsigned short h) {
    unsigned u = ((unsigned)h) << 16;
    return __builtin_bit_cast(float, u);
}

// ---------- K1: transpose x[b][c][j] fp32 -> xt[b][j][c] bf16 ----------
__launch_bounds__(256)
__global__ void k_tr(const float* __restrict__ x, unsigned* __restrict__ xto) {
    __shared__ float s[96 * 133];
    const int b = blockIdx.y, j0 = blockIdx.x * 128, t = threadIdx.x;
    const float* xb = x + (size_t)b * 96 * 16384 + j0;
    for (int q = t; q < 3072; q += 256) {
        int c = q >> 5, j4 = (q & 31) * 4;
        float4 v = *(const float4*)(xb + (size_t)c * 16384 + j4);
        s[c * 133 + j4 + 0] = v.x;
        s[c * 133 + j4 + 1] = v.y;
        s[c * 133 + j4 + 2] = v.z;
        s[c * 133 + j4 + 3] = v.w;
    }
    __syncthreads();
    for (int q = t; q < 6144; q += 256) {
        int cp = q % 48, jj = q / 48;
        float f0 = s[(2 * cp) * 133 + jj];
        float f1 = s[(2 * cp + 1) * 133 + jj];
        unsigned pr = bf16_rne(f0) | (bf16_rne(f1) << 16);
        xto[(size_t)(b * 16384 + j0 + jj) * 48 + cp] = pr;
    }
}

// ---------- K1b: pack weights into B-fragment order ----------
__global__ void k_pack(const float* __restrict__ cw, const float* __restrict__ pw,
                       unsigned short* __restrict__ wB) {
    int e = blockIdx.x * 256 + threadIdx.x;
    if (e >= 110592) return;
    int r = e & 7, l = (e >> 3) & 63;
    int ts = e >> 9;
    int s = ts % 18, ot = ts / 18;
    int o = ot * 16 + (l & 15);
    int ko = s * 32 + ((l >> 4) << 3) + r;
    float v;
    if (ko < 480) { int m = ko / 96, c = ko % 96; v = cw[(o * 96 + c) * 5 + m]; }
    else          { int c = ko - 480;             v = pw[o * 96 + c]; }
    wB[e] = (unsigned short)bf16_rne(v);
}

// ---------- K2: gather + feat -> featA (A-frag order), direct global gather ----------
// block: 192 threads = (c8 0..11, nl 0..15); 16 points per block
__launch_bounds__(192)
__global__ void k_feat(const unsigned short* __restrict__ xt,
                       const int* __restrict__ idx,
                       const float* __restrict__ basis,
                       unsigned short* __restrict__ featA) {
    __shared__ float s_bas[16 * 97];   // [nl][k*6+m]
    __shared__ int s_idx[256];         // [nl*16+kk]
    const int t = threadIdx.x, b = blockIdx.y, n0 = blockIdx.x * 16;

    for (int i = t; i < 256; i += 192)
        s_idx[i] = idx[n0 * 16 + i];
    for (int i = t; i < 16 * 96; i += 192) {
        int nl = i / 96, km = i % 96, k = km / 6, m = km % 6;
        float v = (m < 5) ? basis[((size_t)(n0 + nl) * 16 + k) * 5 + m] : 0.0625f;
        s_bas[nl * 97 + km] = v;
    }
    __syncthreads();

    const int c8 = t >> 4, nl = t & 15;
    float fm[6][8];
#pragma unroll
    for (int m = 0; m < 6; ++m)
#pragma unroll
        for (int j = 0; j < 8; ++j) fm[m][j] = 0.f;

    const size_t xbase = (size_t)b * 16384;
#pragma unroll 4
    for (int k = 0; k < 16; ++k) {
        int j = s_idx[nl * 16 + k];
        s16x8 v = *(const s16x8*)(xt + (xbase + j) * 96 + c8 * 8);
        float gf[8];
#pragma unroll
        for (int q = 0; q < 8; ++q) gf[q] = bf16_f((unsigned short)v[q]);
#pragma unroll
        for (int m = 0; m < 6; ++m) {
            float bv = s_bas[nl * 97 + k * 6 + m];
#pragma unroll
            for (int q = 0; q < 8; ++q) fm[m][q] = fmaf(gf[q], bv, fm[m][q]);
        }
    }

    const int tile = b * 256 + blockIdx.x;
    const int fl = nl + ((c8 & 3) << 4);
#pragma unroll
    for (int m = 0; m < 6; ++m) {
        int s = 3 * m + (c8 >> 2);
        uint4 o;
        o.x = bf16_rne(fm[m][0]) | (bf16_rne(fm[m][1]) << 16);
        o.y = bf16_rne(fm[m][2]) | (bf16_rne(fm[m][3]) << 16);
        o.z = bf16_rne(fm[m][4]) | (bf16_rne(fm[m][5]) << 16);
        o.w = bf16_rne(fm[m][6]) | (bf16_rne(fm[m][7]) << 16);
        *(uint4*)(featA + ((size_t)(tile * 18 + s) * 64 + fl) * 8) = o;
    }
}

// ---------- K3: GEMM via MFMA; bf16 outputs via LDS restage ----------
// block: 64 rows x 192 cols; 4 waves = 2 row x 2 col
__launch_bounds__(256)
__global__ void k_gemm(const unsigned short* __restrict__ featA,
                       const unsigned short* __restrict__ wB,
                       unsigned short* __restrict__ convb,
                       unsigned short* __restrict__ identb) {
    __shared__ __align__(16) unsigned short s_c[192 * 72];  // [o][lr], pad 72
    const int t = threadIdx.x;
    const int w = t >> 6, lane = t & 63;
    const int wr = w & 1, wc = w >> 1;
    const int bid = blockIdx.x;
    const int tile0 = bid * 4 + wr * 2;
    const s16x8* A  = (const s16x8*)featA;
    const s16x8* Bw = (const s16x8*)wB;

    f32x4 accC[2][6], accI[2][6];
    const f32x4 z = {0.f, 0.f, 0.f, 0.f};
#pragma unroll
    for (int rt = 0; rt < 2; ++rt)
#pragma unroll
        for (int j = 0; j < 6; ++j) { accC[rt][j] = z; accI[rt][j] = z; }

    for (int s = 0; s < 15; ++s) {
        s16x8 a0 = A[(size_t)(tile0 * 18 + s) * 64 + lane];
        s16x8 a1 = A[(size_t)((tile0 + 1) * 18 + s) * 64 + lane];
#pragma unroll
        for (int j = 0; j < 6; ++j) {
            s16x8 bf = Bw[(size_t)((wc * 6 + j) * 18 + s) * 64 + lane];
            accC[0][j] = __builtin_amdgcn_mfma_f32_16x16x32_bf16(a0, bf, accC[0][j], 0, 0, 0);
            accC[1][j] = __builtin_amdgcn_mfma_f32_16x16x32_bf16(a1, bf, accC[1][j], 0, 0, 0);
        }
    }
#pragma unroll
    for (int s = 15; s < 18; ++s) {
        s16x8 a0 = A[(size_t)(tile0 * 18 + s) * 64 + lane];
        s16x8 a1 = A[(size_t)((tile0 + 1) * 18 + s) * 64 + lane];
#pragma unroll
        for (int j = 0; j < 6; ++j) {
            s16x8 bf = Bw[(size_t)((wc * 6 + j) * 18 + s) * 64 + lane];
            accI[0][j] = __builtin_amdgcn_mfma_f32_16x16x32_bf16(a0, bf, accI[0][j], 0, 0, 0);
            accI[1][j] = __builtin_amdgcn_mfma_f32_16x16x32_bf16(a1, bf, accI[1][j], 0, 0, 0);
        }
    }

    const int col_l = lane & 15, rg = (lane >> 4) * 4;
    const int b  = (bid * 64) >> 12;
    const int n0 = (bid * 64) & 4095;

    // phase A: conv
#pragma unroll
    for (int rt = 0; rt < 2; ++rt) {
        int lr = (wr * 2 + rt) * 16 + rg;
#pragma unroll
        for (int j = 0; j < 6; ++j) {
            int o = (wc * 6 + j) * 16 + col_l;
#pragma unroll
            for (int r = 0; r < 4; ++r)
                s_c[o * 72 + lr + r] = (unsigned short)bf16_rne(accC[rt][j][r]);
        }
    }
    __syncthreads();
    for (int u = t; u < 1536; u += 256) {
        int o = u >> 3, part = u & 7;
        uint4 v = *(const uint4*)(&s_c[o * 72 + part * 8]);
        *(uint4*)(convb + ((size_t)(b * 192 + o)) * 4096 + n0 + part * 8) = v;
    }
    __syncthreads();
    // phase B: ident
#pragma unroll
    for (int rt = 0; rt < 2; ++rt) {
        int lr = (wr * 2 + rt) * 16 + rg;
#pragma unroll
        for (int j = 0; j < 6; ++j) {
            int o = (wc * 6 + j) * 16 + col_l;
#pragma unroll
            for (int r = 0; r < 4; ++r)
                s_c[o * 72 + lr + r] = (unsigned short)bf16_rne(accI[rt][j][r]);
        }
    }
    __syncthreads();
    for (int u = t; u < 1536; u += 256) {
        int o = u >> 3, part = u & 7;
        uint4 v = *(const uint4*)(&s_c[o * 72 + part * 8]);
        *(uint4*)(identb + ((size_t)(b * 192 + o)) * 4096 + n0 + part * 8) = v;
    }
}

// ---------- K4: per-channel BN stats from bf16 conv ----------
__launch_bounds__(256)
__global__ void k_stats(const unsigned short* __restrict__ convb,
                        const float* __restrict__ gamma,
                        const float* __restrict__ beta,
                        const float* __restrict__ pool_b,
                        float* __restrict__ ss) {
    int o = blockIdx.x, t = threadIdx.x;
    float s1 = 0.f, s2 = 0.f;
    for (int b = 0; b < cB; ++b) {
        const uint4* p = (const uint4*)(convb + ((size_t)b * cCOUT + o) * cNOUT);
        for (int q = t; q < 512; q += 256) {
            uint4 v = p[q];
            const unsigned short* h = (const unsigned short*)&v;
#pragma unroll
            for (int j = 0; j < 8; ++j) {
                float f = bf16_f(h[j]);
                s1 += f;
                s2 = fmaf(f, f, s2);
            }
        }
    }
#pragma unroll
    for (int off = 32; off; off >>= 1) {
        s1 += __shfl_down(s1, off);
        s2 += __shfl_down(s2, off);
    }
    __shared__ float w1[4], w2[4];
    int lane = t & 63, wid = t >> 6;
    if (lane == 0) { w1[wid] = s1; w2[wid] = s2; }
    __syncthreads();
    if (t == 0) {
        float S1 = w1[0] + w1[1] + w1[2] + w1[3];
        float S2 = w2[0] + w2[1] + w2[2] + w2[3];
        float inv  = 1.0f / (cB * cNOUT);
        float mean = S1 * inv;
        float var  = S2 * inv - mean * mean;
        float scale = gamma[o] * rsqrtf(var + cEPS);
        ss[o]         = scale;
        ss[cCOUT + o] = beta[o] - mean * scale + pool_b[o];
    }
}

// ---------- K5: BN apply + residual ----------
__launch_bounds__(256)
__global__ void k_final(const unsigned short* __restrict__ convb,
                        const unsigned short* __restrict__ identb,
                        const float* __restrict__ ss,
                        float* __restrict__ out) {
    size_t i = ((size_t)blockIdx.x * 256 + threadIdx.x) * 8;
    int o = (int)((i >> 12) % cCOUT);
    uint4 cv = *(const uint4*)(convb + i);
    uint4 dv = *(const uint4*)(identb + i);
    const unsigned short* ch = (const unsigned short*)&cv;
    const unsigned short* dh = (const unsigned short*)&dv;
    float sc = ss[o], sh = ss[cCOUT + o];
    float r[8];
#pragma unroll
    for (int j = 0; j < 8; ++j)
        r[j] = fmaf(bf16_f(ch[j]), sc, sh + bf16_f(dh[j]));
    *(float4*)(out + i)     = *(float4*)&r[0];
    *(float4*)(out + i + 4) = *(float4*)&r[4];
}

extern "C" void kernel_launch(void* const* d_in, const int* in_sizes, int n_in,
                              void* d_out, int out_size, void* d_ws, size_t ws_size,
                              hipStream_t stream) {
    const float* x      = (const float*)d_in[0];
    const int*   idx    = (const int*)d_in[1];
    const float* basis  = (const float*)d_in[2];
    const float* conv_w = (const float*)d_in[3];
    const float* pool_w = (const float*)d_in[5];
    const float* pool_b = (const float*)d_in[6];
    const float* gamma  = (const float*)d_in[7];
    const float* beta   = (const float*)d_in[8];
    float* out = (float*)d_out;

    char* wsb = (char*)d_ws;
    unsigned short* xt     = (unsigned short*)(wsb + OFF_XT);
    unsigned short* convb  = (unsigned short*)(wsb + OFF_CONVB);   // aliases xt (dead)
    unsigned short* identb = (unsigned short*)(wsb + OFF_IDENTB);  // aliases xt (dead)
    unsigned short* featA  = (unsigned short*)(wsb + OFF_FEATA);
    unsigned short* wB     = (unsigned short*)(wsb + OFF_WB);
    float*          ss     = (float*)(wsb + OFF_SS);

    k_tr   <<<dim3(cNIN / 128, cB), 256, 0, stream>>>(x, (unsigned*)xt);
    k_pack <<<(110592 + 255) / 256, 256, 0, stream>>>(conv_w, pool_w, wB);
    k_feat <<<dim3(cNOUT / 16, cB), 192, 0, stream>>>(xt, idx, basis, featA);
    k_gemm <<<(cB * cNOUT) / 64, 256, 0, stream>>>(featA, wB, convb, identb);
    k_stats<<<cCOUT, 256, 0, stream>>>(convb, gamma, beta, pool_b, ss);
    k_final<<<(size_t)cB * cCOUT * cNOUT / 2048, 256, 0, stream>>>(convb, identb, ss, out);
}

// Round 6
// 145.507 us; speedup vs baseline: 6.2131x; 1.0321x over previous
//
#include <hip/hip_runtime.h>

typedef __attribute__((ext_vector_type(8))) short s16x8;
typedef __attribute__((ext_vector_type(4))) float f32x4;

constexpr int cB = 16, cCIN = 96, cCOUT = 192, cNIN = 16384, cNOUT = 4096;
constexpr float cEPS = 1e-5f;

// ws layout (bytes) — round-3 verified layout + partials scratch
constexpr size_t OFF_XT     = 0;           // bf16 xt[b][j][c]  50,331,648 (dead after k_feat)
constexpr size_t OFF_CONVB  = 0;           // bf16 conv[b][o][n] 25,165,824 (aliases dead xt)
constexpr size_t OFF_IDENTB = 25165824;    // bf16 ident[b][o][n] 25,165,824 (aliases dead xt)
constexpr size_t OFF_FEATA  = 50331648;    // bf16 frag-order feat 75,497,472
constexpr size_t OFF_WB     = 125829120;   // bf16 frag-order W 221,184
constexpr size_t OFF_SS     = 126050304;   // fp32 scale/shift 1,536
constexpr size_t OFF_S1     = 126051840;   // fp32 partials1[o][2048] 1,572,864
constexpr size_t OFF_S2     = 127624704;   // fp32 partials2[o][2048] 1,572,864

__device__ inline unsigned bf16_rne(float f) {
    unsigned u = __builtin_bit_cast(unsigned, f);
    return (u + 0x7fffu + ((u >> 16) & 1u)) >> 16;
}
__device__ inline float bf16_f(unsigned short h) {
    unsigned u = ((unsigned)h) << 16;
    return __builtin_bit_cast(float, u);
}

// ---------- K1: transpose x[b][c][j] fp32 -> xt[b][j][c] bf16 ----------
__launch_bounds__(256)
__global__ void k_tr(const float* __restrict__ x, unsigned* __restrict__ xto) {
    __shared__ float s[96 * 133];
    const int b = blockIdx.y, j0 = blockIdx.x * 128, t = threadIdx.x;
    const float* xb = x + (size_t)b * 96 * 16384 + j0;
    for (int q = t; q < 3072; q += 256) {
        int c = q >> 5, j4 = (q & 31) * 4;
        float4 v = *(const float4*)(xb + (size_t)c * 16384 + j4);
        s[c * 133 + j4 + 0] = v.x;
        s[c * 133 + j4 + 1] = v.y;
        s[c * 133 + j4 + 2] = v.z;
        s[c * 133 + j4 + 3] = v.w;
    }
    __syncthreads();
    for (int q = t; q < 6144; q += 256) {
        int cp = q % 48, jj = q / 48;
        float f0 = s[(2 * cp) * 133 + jj];
        float f1 = s[(2 * cp + 1) * 133 + jj];
        unsigned pr = bf16_rne(f0) | (bf16_rne(f1) << 16);
        xto[(size_t)(b * 16384 + j0 + jj) * 48 + cp] = pr;
    }
}

// ---------- K1b: pack weights into B-fragment order ----------
__global__ void k_pack(const float* __restrict__ cw, const float* __restrict__ pw,
                       unsigned short* __restrict__ wB) {
    int e = blockIdx.x * 256 + threadIdx.x;
    if (e >= 110592) return;
    int r = e & 7, l = (e >> 3) & 63;
    int ts = e >> 9;
    int s = ts % 18, ot = ts / 18;
    int o = ot * 16 + (l & 15);
    int ko = s * 32 + ((l >> 4) << 3) + r;
    float v;
    if (ko < 480) { int m = ko / 96, c = ko % 96; v = cw[(o * 96 + c) * 5 + m]; }
    else          { int c = ko - 480;             v = pw[o * 96 + c]; }
    wB[e] = (unsigned short)bf16_rne(v);
}

// ---------- K2: gather + feat -> featA (A-frag order), direct global gather ----------
// block: 192 threads = (c8 0..11, nl 0..15); 16 points per block
__launch_bounds__(192)
__global__ void k_feat(const unsigned short* __restrict__ xt,
                       const int* __restrict__ idx,
                       const float* __restrict__ basis,
                       unsigned short* __restrict__ featA) {
    __shared__ float s_bas[16 * 97];   // [nl][k*6+m]
    __shared__ int s_idx[256];         // [nl*16+kk]
    const int t = threadIdx.x, b = blockIdx.y, n0 = blockIdx.x * 16;

    for (int i = t; i < 256; i += 192)
        s_idx[i] = idx[n0 * 16 + i];
    for (int i = t; i < 16 * 96; i += 192) {
        int nl = i / 96, km = i % 96, k = km / 6, m = km % 6;
        float v = (m < 5) ? basis[((size_t)(n0 + nl) * 16 + k) * 5 + m] : 0.0625f;
        s_bas[nl * 97 + km] = v;
    }
    __syncthreads();

    const int c8 = t >> 4, nl = t & 15;
    float fm[6][8];
#pragma unroll
    for (int m = 0; m < 6; ++m)
#pragma unroll
        for (int j = 0; j < 8; ++j) fm[m][j] = 0.f;

    const size_t xbase = (size_t)b * 16384;
#pragma unroll 4
    for (int k = 0; k < 16; ++k) {
        int j = s_idx[nl * 16 + k];
        s16x8 v = *(const s16x8*)(xt + (xbase + j) * 96 + c8 * 8);
        float gf[8];
#pragma unroll
        for (int q = 0; q < 8; ++q) gf[q] = bf16_f((unsigned short)v[q]);
#pragma unroll
        for (int m = 0; m < 6; ++m) {
            float bv = s_bas[nl * 97 + k * 6 + m];
#pragma unroll
            for (int q = 0; q < 8; ++q) fm[m][q] = fmaf(gf[q], bv, fm[m][q]);
        }
    }

    const int tile = b * 256 + blockIdx.x;
    const int fl = nl + ((c8 & 3) << 4);
#pragma unroll
    for (int m = 0; m < 6; ++m) {
        int s = 3 * m + (c8 >> 2);
        uint4 o;
        o.x = bf16_rne(fm[m][0]) | (bf16_rne(fm[m][1]) << 16);
        o.y = bf16_rne(fm[m][2]) | (bf16_rne(fm[m][3]) << 16);
        o.z = bf16_rne(fm[m][4]) | (bf16_rne(fm[m][5]) << 16);
        o.w = bf16_rne(fm[m][6]) | (bf16_rne(fm[m][7]) << 16);
        *(uint4*)(featA + ((size_t)(tile * 18 + s) * 64 + fl) * 8) = o;
    }
}

// ---------- K3: GEMM via MFMA; bf16 outputs via LDS restage + register BN partials ----------
// block: 64 rows x 192 cols; 4 waves = 2 row x 2 col
__launch_bounds__(256)
__global__ void k_gemm(const unsigned short* __restrict__ featA,
                       const unsigned short* __restrict__ wB,
                       unsigned short* __restrict__ convb,
                       unsigned short* __restrict__ identb,
                       float* __restrict__ s1g,
                       float* __restrict__ s2g) {
    __shared__ __align__(16) unsigned short s_c[192 * 72];  // [o][lr], pad 72
    const int t = threadIdx.x;
    const int w = t >> 6, lane = t & 63;
    const int wr = w & 1, wc = w >> 1;
    const int bid = blockIdx.x;
    const int tile0 = bid * 4 + wr * 2;
    const s16x8* A  = (const s16x8*)featA;
    const s16x8* Bw = (const s16x8*)wB;

    f32x4 accC[2][6], accI[2][6];
    const f32x4 z = {0.f, 0.f, 0.f, 0.f};
#pragma unroll
    for (int rt = 0; rt < 2; ++rt)
#pragma unroll
        for (int j = 0; j < 6; ++j) { accC[rt][j] = z; accI[rt][j] = z; }

    for (int s = 0; s < 15; ++s) {
        s16x8 a0 = A[(size_t)(tile0 * 18 + s) * 64 + lane];
        s16x8 a1 = A[(size_t)((tile0 + 1) * 18 + s) * 64 + lane];
#pragma unroll
        for (int j = 0; j < 6; ++j) {
            s16x8 bf = Bw[(size_t)((wc * 6 + j) * 18 + s) * 64 + lane];
            accC[0][j] = __builtin_amdgcn_mfma_f32_16x16x32_bf16(a0, bf, accC[0][j], 0, 0, 0);
            accC[1][j] = __builtin_amdgcn_mfma_f32_16x16x32_bf16(a1, bf, accC[1][j], 0, 0, 0);
        }
    }
#pragma unroll
    for (int s = 15; s < 18; ++s) {
        s16x8 a0 = A[(size_t)(tile0 * 18 + s) * 64 + lane];
        s16x8 a1 = A[(size_t)((tile0 + 1) * 18 + s) * 64 + lane];
#pragma unroll
        for (int j = 0; j < 6; ++j) {
            s16x8 bf = Bw[(size_t)((wc * 6 + j) * 18 + s) * 64 + lane];
            accI[0][j] = __builtin_amdgcn_mfma_f32_16x16x32_bf16(a0, bf, accI[0][j], 0, 0, 0);
            accI[1][j] = __builtin_amdgcn_mfma_f32_16x16x32_bf16(a1, bf, accI[1][j], 0, 0, 0);
        }
    }

    const int col_l = lane & 15, rg = (lane >> 4) * 4;
    const int b  = (bid * 64) >> 12;
    const int n0 = (bid * 64) & 4095;

    // ---- register-sourced BN partials (conv path only) ----
#pragma unroll
    for (int j = 0; j < 6; ++j) {
        float s1 = 0.f, s2 = 0.f;
#pragma unroll
        for (int rt = 0; rt < 2; ++rt)
#pragma unroll
            for (int r = 0; r < 4; ++r) {
                float v = accC[rt][j][r];
                s1 += v;
                s2 = fmaf(v, v, s2);
            }
        s1 += __shfl_xor(s1, 16); s2 += __shfl_xor(s2, 16);
        s1 += __shfl_xor(s1, 32); s2 += __shfl_xor(s2, 32);
        if (lane < 16) {
            int o = (wc * 6 + j) * 16 + lane;
            s1g[(size_t)o * 2048 + bid * 2 + wr] = s1;
            s2g[(size_t)o * 2048 + bid * 2 + wr] = s2;
        }
    }

    // phase A: conv
#pragma unroll
    for (int rt = 0; rt < 2; ++rt) {
        int lr = (wr * 2 + rt) * 16 + rg;
#pragma unroll
        for (int j = 0; j < 6; ++j) {
            int o = (wc * 6 + j) * 16 + col_l;
#pragma unroll
            for (int r = 0; r < 4; ++r)
                s_c[o * 72 + lr + r] = (unsigned short)bf16_rne(accC[rt][j][r]);
        }
    }
    __syncthreads();
    for (int u = t; u < 1536; u += 256) {
        int o = u >> 3, part = u & 7;
        uint4 v = *(const uint4*)(&s_c[o * 72 + part * 8]);
        *(uint4*)(convb + ((size_t)(b * 192 + o)) * 4096 + n0 + part * 8) = v;
    }
    __syncthreads();
    // phase B: ident
#pragma unroll
    for (int rt = 0; rt < 2; ++rt) {
        int lr = (wr * 2 + rt) * 16 + rg;
#pragma unroll
        for (int j = 0; j < 6; ++j) {
            int o = (wc * 6 + j) * 16 + col_l;
#pragma unroll
            for (int r = 0; r < 4; ++r)
                s_c[o * 72 + lr + r] = (unsigned short)bf16_rne(accI[rt][j][r]);
        }
    }
    __syncthreads();
    for (int u = t; u < 1536; u += 256) {
        int o = u >> 3, part = u & 7;
        uint4 v = *(const uint4*)(&s_c[o * 72 + part * 8]);
        *(uint4*)(identb + ((size_t)(b * 192 + o)) * 4096 + n0 + part * 8) = v;
    }
}

// ---------- K4: reduce partials -> scale/shift ----------
__launch_bounds__(256)
__global__ void k_ss(const float* __restrict__ s1g, const float* __restrict__ s2g,
                     const float* __restrict__ gamma, const float* __restrict__ beta,
                     const float* __restrict__ pool_b, float* __restrict__ ss) {
    int o = blockIdx.x, t = threadIdx.x;
    float s1 = 0.f, s2 = 0.f;
    for (int i = t; i < 2048; i += 256) {
        s1 += s1g[(size_t)o * 2048 + i];
        s2 += s2g[(size_t)o * 2048 + i];
    }
#pragma unroll
    for (int off = 32; off; off >>= 1) {
        s1 += __shfl_down(s1, off);
        s2 += __shfl_down(s2, off);
    }
    __shared__ float w1[4], w2[4];
    int lane = t & 63, wid = t >> 6;
    if (lane == 0) { w1[wid] = s1; w2[wid] = s2; }
    __syncthreads();
    if (t == 0) {
        float S1 = w1[0] + w1[1] + w1[2] + w1[3];
        float S2 = w2[0] + w2[1] + w2[2] + w2[3];
        float inv  = 1.0f / (cB * cNOUT);
        float mean = S1 * inv;
        float var  = S2 * inv - mean * mean;
        float scale = gamma[o] * rsqrtf(var + cEPS);
        ss[o]         = scale;
        ss[cCOUT + o] = beta[o] - mean * scale + pool_b[o];
    }
}

// ---------- K5: BN apply + residual ----------
__launch_bounds__(256)
__global__ void k_final(const unsigned short* __restrict__ convb,
                        const unsigned short* __restrict__ identb,
                        const float* __restrict__ ss,
                        float* __restrict__ out) {
    size_t i = ((size_t)blockIdx.x * 256 + threadIdx.x) * 8;
    int o = (int)((i >> 12) % cCOUT);
    uint4 cv = *(const uint4*)(convb + i);
    uint4 dv = *(const uint4*)(identb + i);
    const unsigned short* ch = (const unsigned short*)&cv;
    const unsigned short* dh = (const unsigned short*)&dv;
    float sc = ss[o], sh = ss[cCOUT + o];
    float r[8];
#pragma unroll
    for (int j = 0; j < 8; ++j)
        r[j] = fmaf(bf16_f(ch[j]), sc, sh + bf16_f(dh[j]));
    *(float4*)(out + i)     = *(float4*)&r[0];
    *(float4*)(out + i + 4) = *(float4*)&r[4];
}

extern "C" void kernel_launch(void* const* d_in, const int* in_sizes, int n_in,
                              void* d_out, int out_size, void* d_ws, size_t ws_size,
                              hipStream_t stream) {
    const float* x      = (const float*)d_in[0];
    const int*   idx    = (const int*)d_in[1];
    const float* basis  = (const float*)d_in[2];
    const float* conv_w = (const float*)d_in[3];
    // d_in[4] = conv_b cancels under BN -> unused
    const float* pool_w = (const float*)d_in[5];
    const float* pool_b = (const float*)d_in[6];
    const float* gamma  = (const float*)d_in[7];
    const float* beta   = (const float*)d_in[8];
    float* out = (float*)d_out;

    char* wsb = (char*)d_ws;
    unsigned short* xt     = (unsigned short*)(wsb + OFF_XT);
    unsigned short* convb  = (unsigned short*)(wsb + OFF_CONVB);   // aliases xt (dead)
    unsigned short* identb = (unsigned short*)(wsb + OFF_IDENTB);  // aliases xt (dead)
    unsigned short* featA  = (unsigned short*)(wsb + OFF_FEATA);
    unsigned short* wB     = (unsigned short*)(wsb + OFF_WB);
    float*          ss     = (float*)(wsb + OFF_SS);
    float*          s1g    = (float*)(wsb + OFF_S1);
    float*          s2g    = (float*)(wsb + OFF_S2);

    k_tr   <<<dim3(cNIN / 128, cB), 256, 0, stream>>>(x, (unsigned*)xt);
    k_pack <<<(110592 + 255) / 256, 256, 0, stream>>>(conv_w, pool_w, wB);
    k_feat <<<dim3(cNOUT / 16, cB), 192, 0, stream>>>(xt, idx, basis, featA);
    k_gemm <<<(cB * cNOUT) / 64, 256, 0, stream>>>(featA, wB, convb, identb, s1g, s2g);
    k_ss   <<<cCOUT, 256, 0, stream>>>(s1g, s2g, gamma, beta, pool_b, ss);
    k_final<<<(size_t)cB * cCOUT * cNOUT / 2048, 256, 0, stream>>>(convb, identb, ss, out);
}

// Round 9
// 134.936 us; speedup vs baseline: 6.6999x; 1.0783x over previous
//
#include <hip/hip_runtime.h>

typedef __attribute__((ext_vector_type(8))) short s16x8;
typedef __attribute__((ext_vector_type(4))) float f32x4;

constexpr int cB = 16, cCIN = 96, cCOUT = 192, cNIN = 16384, cNOUT = 4096;
constexpr float cEPS = 1e-5f;

// ws layout (bytes) — round-6 verified (xt aliased by convb/identb is SAFE here:
// kernel boundary between k_feat (last xt read) and k_gemm (first convb write))
constexpr size_t OFF_XT     = 0;           // bf16 xt[b][j][c]  50,331,648 (dead after k_feat)
constexpr size_t OFF_CONVB  = 0;           // bf16 conv[b][o][n] 25,165,824 (aliases dead xt)
constexpr size_t OFF_IDENTB = 25165824;    // bf16 ident[b][o][n] 25,165,824 (aliases dead xt)
constexpr size_t OFF_FEATA  = 50331648;    // bf16 frag-order feat 75,497,472
constexpr size_t OFF_WB     = 125829120;   // bf16 frag-order W 221,184
constexpr size_t OFF_SS     = 126050304;   // fp32 scale/shift 1,536
constexpr size_t OFF_S1     = 126051840;   // fp32 partials1[o][2048] 1,572,864
constexpr size_t OFF_S2     = 127624704;   // fp32 partials2[o][2048] 1,572,864

__device__ inline unsigned bf16_rne(float f) {
    unsigned u = __builtin_bit_cast(unsigned, f);
    return (u + 0x7fffu + ((u >> 16) & 1u)) >> 16;
}
__device__ inline float bf16_f(unsigned short h) {
    unsigned u = ((unsigned)h) << 16;
    return __builtin_bit_cast(float, u);
}

// ---------- K1: transpose x[b][c][j] fp32 -> xt[b][j][c] bf16 ----------
__launch_bounds__(256)
__global__ void k_tr(const float* __restrict__ x, unsigned* __restrict__ xto) {
    __shared__ float s[96 * 133];
    const int b = blockIdx.y, j0 = blockIdx.x * 128, t = threadIdx.x;
    const float* xb = x + (size_t)b * 96 * 16384 + j0;
    for (int q = t; q < 3072; q += 256) {
        int c = q >> 5, j4 = (q & 31) * 4;
        float4 v = *(const float4*)(xb + (size_t)c * 16384 + j4);
        s[c * 133 + j4 + 0] = v.x;
        s[c * 133 + j4 + 1] = v.y;
        s[c * 133 + j4 + 2] = v.z;
        s[c * 133 + j4 + 3] = v.w;
    }
    __syncthreads();
    for (int q = t; q < 3072; q += 256) {
        int cp2 = q % 24, jj = q / 24;
        float f0 = s[(4 * cp2 + 0) * 133 + jj];
        float f1 = s[(4 * cp2 + 1) * 133 + jj];
        float f2 = s[(4 * cp2 + 2) * 133 + jj];
        float f3 = s[(4 * cp2 + 3) * 133 + jj];
        uint2 pr;
        pr.x = bf16_rne(f0) | (bf16_rne(f1) << 16);
        pr.y = bf16_rne(f2) | (bf16_rne(f3) << 16);
        *(uint2*)(xto + (size_t)(b * 16384 + j0 + jj) * 48 + cp2 * 2) = pr;
    }
}

// ---------- K1b: pack weights into B-fragment order ----------
__global__ void k_pack(const float* __restrict__ cw, const float* __restrict__ pw,
                       unsigned short* __restrict__ wB) {
    int e = blockIdx.x * 256 + threadIdx.x;
    if (e >= 110592) return;
    int r = e & 7, l = (e >> 3) & 63;
    int ts = e >> 9;
    int s = ts % 18, ot = ts / 18;
    int o = ot * 16 + (l & 15);
    int ko = s * 32 + ((l >> 4) << 3) + r;
    float v;
    if (ko < 480) { int m = ko / 96, c = ko % 96; v = cw[(o * 96 + c) * 5 + m]; }
    else          { int c = ko - 480;             v = pw[o * 96 + c]; }
    wB[e] = (unsigned short)bf16_rne(v);
}

// ---------- K2: gather + feat -> featA (A-frag order), XCD-swizzled ----------
// 4096 blocks x 192 threads; xcd = wg&7 owns b = xcd*2 + (slot>>8) (3.1MB slab L2-resident)
__launch_bounds__(192)
__global__ void k_feat(const unsigned short* __restrict__ xt,
                       const int* __restrict__ idx,
                       const float* __restrict__ basis,
                       unsigned short* __restrict__ featA) {
    __shared__ float s_bas[16 * 97];   // [nl][k*6+m]
    __shared__ int s_idx[256];         // [nl*16+kk]
    const int t = threadIdx.x;
    const int wg = blockIdx.x;
    const int xcd = wg & 7, slot = wg >> 3;
    const int b  = xcd * 2 + (slot >> 8);
    const int nt = slot & 255;
    const int n0 = nt * 16;

    for (int i = t; i < 256; i += 192)
        s_idx[i] = idx[n0 * 16 + i];
    for (int i = t; i < 16 * 96; i += 192) {
        int nl = i / 96, km = i % 96, k = km / 6, m = km % 6;
        float v = (m < 5) ? basis[((size_t)(n0 + nl) * 16 + k) * 5 + m] : 0.0625f;
        s_bas[nl * 97 + km] = v;
    }
    __syncthreads();

    const int c8 = t >> 4, nl = t & 15;
    float fm[6][8];
#pragma unroll
    for (int m = 0; m < 6; ++m)
#pragma unroll
        for (int j = 0; j < 8; ++j) fm[m][j] = 0.f;

    const size_t xbase = (size_t)b * 16384;
#pragma unroll 4
    for (int k = 0; k < 16; ++k) {
        int j = s_idx[nl * 16 + k];
        s16x8 v = *(const s16x8*)(xt + (xbase + j) * 96 + c8 * 8);
        float gf[8];
#pragma unroll
        for (int q = 0; q < 8; ++q) gf[q] = bf16_f((unsigned short)v[q]);
#pragma unroll
        for (int m = 0; m < 6; ++m) {
            float bv = s_bas[nl * 97 + k * 6 + m];
#pragma unroll
            for (int q = 0; q < 8; ++q) fm[m][q] = fmaf(gf[q], bv, fm[m][q]);
        }
    }

    const int tile = b * 256 + nt;
    const int fl = nl + ((c8 & 3) << 4);
#pragma unroll
    for (int m = 0; m < 6; ++m) {
        int s = 3 * m + (c8 >> 2);
        uint4 o;
        o.x = bf16_rne(fm[m][0]) | (bf16_rne(fm[m][1]) << 16);
        o.y = bf16_rne(fm[m][2]) | (bf16_rne(fm[m][3]) << 16);
        o.z = bf16_rne(fm[m][4]) | (bf16_rne(fm[m][5]) << 16);
        o.w = bf16_rne(fm[m][6]) | (bf16_rne(fm[m][7]) << 16);
        *(uint4*)(featA + ((size_t)(tile * 18 + s) * 64 + fl) * 8) = o;
    }
}

// ---------- K3: GEMM via MFMA; accI split out of main loop; prefetched A ----------
// block: 64 rows x 192 cols; 4 waves = 2 row x 2 col
__launch_bounds__(256, 3)
__global__ void k_gemm(const unsigned short* __restrict__ featA,
                       const unsigned short* __restrict__ wB,
                       unsigned short* __restrict__ convb,
                       unsigned short* __restrict__ identb,
                       float* __restrict__ s1g,
                       float* __restrict__ s2g) {
    __shared__ __align__(16) unsigned short s_c[192 * 72];  // [o][lr], pad 72
    const int t = threadIdx.x;
    const int w = t >> 6, lane = t & 63;
    const int wr = w & 1, wc = w >> 1;
    const int bid = blockIdx.x;
    const int tile0 = bid * 4 + wr * 2;
    const s16x8* A  = (const s16x8*)featA;
    const s16x8* Bw = (const s16x8*)wB;

    const f32x4 z = {0.f, 0.f, 0.f, 0.f};
    f32x4 accC[2][6];
#pragma unroll
    for (int rt = 0; rt < 2; ++rt)
#pragma unroll
        for (int j = 0; j < 6; ++j) accC[rt][j] = z;

    // ---- main loop: conv K-range s=0..14, software-prefetched A ----
    s16x8 a0 = A[(size_t)(tile0 * 18 + 0) * 64 + lane];
    s16x8 a1 = A[(size_t)((tile0 + 1) * 18 + 0) * 64 + lane];
    for (int s = 0; s < 15; ++s) {
        s16x8 na0 = A[(size_t)(tile0 * 18 + s + 1) * 64 + lane];       // s+1 <= 15: valid
        s16x8 na1 = A[(size_t)((tile0 + 1) * 18 + s + 1) * 64 + lane];
#pragma unroll
        for (int j = 0; j < 6; ++j) {
            s16x8 bf = Bw[(size_t)((wc * 6 + j) * 18 + s) * 64 + lane];
            accC[0][j] = __builtin_amdgcn_mfma_f32_16x16x32_bf16(a0, bf, accC[0][j], 0, 0, 0);
            accC[1][j] = __builtin_amdgcn_mfma_f32_16x16x32_bf16(a1, bf, accC[1][j], 0, 0, 0);
        }
        a0 = na0; a1 = na1;
    }

    const int col_l = lane & 15, rg = (lane >> 4) * 4;
    const int b  = (bid * 64) >> 12;
    const int n0 = (bid * 64) & 4095;

    // ---- register-sourced BN partials (conv path only) ----
#pragma unroll
    for (int j = 0; j < 6; ++j) {
        float s1 = 0.f, s2 = 0.f;
#pragma unroll
        for (int rt = 0; rt < 2; ++rt)
#pragma unroll
            for (int r = 0; r < 4; ++r) {
                float v = accC[rt][j][r];
                s1 += v;
                s2 = fmaf(v, v, s2);
            }
        s1 += __shfl_xor(s1, 16); s2 += __shfl_xor(s2, 16);
        s1 += __shfl_xor(s1, 32); s2 += __shfl_xor(s2, 32);
        if (lane < 16) {
            int o = (wc * 6 + j) * 16 + lane;
            s1g[(size_t)o * 2048 + bid * 2 + wr] = s1;
            s2g[(size_t)o * 2048 + bid * 2 + wr] = s2;
        }
    }

    // ---- phase A: conv -> s_c -> global ----
#pragma unroll
    for (int rt = 0; rt < 2; ++rt) {
        int lr = (wr * 2 + rt) * 16 + rg;
#pragma unroll
        for (int j = 0; j < 6; ++j) {
            int o = (wc * 6 + j) * 16 + col_l;
#pragma unroll
            for (int r = 0; r < 4; ++r)
                s_c[o * 72 + lr + r] = (unsigned short)bf16_rne(accC[rt][j][r]);
        }
    }
    __syncthreads();
    for (int u = t; u < 1536; u += 256) {
        int o = u >> 3, part = u & 7;
        uint4 v = *(const uint4*)(&s_c[o * 72 + part * 8]);
        *(uint4*)(convb + ((size_t)(b * 192 + o)) * 4096 + n0 + part * 8) = v;
    }
    __syncthreads();

    // ---- identity tail: s=15..17 (accC dead; registers freed) ----
    f32x4 accI[2][6];
#pragma unroll
    for (int rt = 0; rt < 2; ++rt)
#pragma unroll
        for (int j = 0; j < 6; ++j) accI[rt][j] = z;
#pragma unroll
    for (int s = 15; s < 18; ++s) {
        s16x8 b0 = A[(size_t)(tile0 * 18 + s) * 64 + lane];
        s16x8 b1 = A[(size_t)((tile0 + 1) * 18 + s) * 64 + lane];
#pragma unroll
        for (int j = 0; j < 6; ++j) {
            s16x8 bf = Bw[(size_t)((wc * 6 + j) * 18 + s) * 64 + lane];
            accI[0][j] = __builtin_amdgcn_mfma_f32_16x16x32_bf16(b0, bf, accI[0][j], 0, 0, 0);
            accI[1][j] = __builtin_amdgcn_mfma_f32_16x16x32_bf16(b1, bf, accI[1][j], 0, 0, 0);
        }
    }

    // ---- phase B: ident -> s_c -> global ----
#pragma unroll
    for (int rt = 0; rt < 2; ++rt) {
        int lr = (wr * 2 + rt) * 16 + rg;
#pragma unroll
        for (int j = 0; j < 6; ++j) {
            int o = (wc * 6 + j) * 16 + col_l;
#pragma unroll
            for (int r = 0; r < 4; ++r)
                s_c[o * 72 + lr + r] = (unsigned short)bf16_rne(accI[rt][j][r]);
        }
    }
    __syncthreads();
    for (int u = t; u < 1536; u += 256) {
        int o = u >> 3, part = u & 7;
        uint4 v = *(const uint4*)(&s_c[o * 72 + part * 8]);
        *(uint4*)(identb + ((size_t)(b * 192 + o)) * 4096 + n0 + part * 8) = v;
    }
}

// ---------- K4: reduce partials -> scale/shift ----------
__launch_bounds__(256)
__global__ void k_ss(const float* __restrict__ s1g, const float* __restrict__ s2g,
                     const float* __restrict__ gamma, const float* __restrict__ beta,
                     const float* __restrict__ pool_b, float* __restrict__ ss) {
    int o = blockIdx.x, t = threadIdx.x;
    float s1 = 0.f, s2 = 0.f;
    for (int i = t; i < 2048; i += 256) {
        s1 += s1g[(size_t)o * 2048 + i];
        s2 += s2g[(size_t)o * 2048 + i];
    }
#pragma unroll
    for (int off = 32; off; off >>= 1) {
        s1 += __shfl_down(s1, off);
        s2 += __shfl_down(s2, off);
    }
    __shared__ float w1[4], w2[4];
    int lane = t & 63, wid = t >> 6;
    if (lane == 0) { w1[wid] = s1; w2[wid] = s2; }
    __syncthreads();
    if (t == 0) {
        float S1 = w1[0] + w1[1] + w1[2] + w1[3];
        float S2 = w2[0] + w2[1] + w2[2] + w2[3];
        float inv  = 1.0f / (cB * cNOUT);
        float mean = S1 * inv;
        float var  = S2 * inv - mean * mean;
        float scale = gamma[o] * rsqrtf(var + cEPS);
        ss[o]         = scale;
        ss[cCOUT + o] = beta[o] - mean * scale + pool_b[o];
    }
}

// ---------- K5: BN apply + residual ----------
__launch_bounds__(256)
__global__ void k_final(const unsigned short* __restrict__ convb,
                        const unsigned short* __restrict__ identb,
                        const float* __restrict__ ss,
                        float* __restrict__ out) {
    size_t i = ((size_t)blockIdx.x * 256 + threadIdx.x) * 8;
    int o = (int)((i >> 12) % cCOUT);
    uint4 cv = *(const uint4*)(convb + i);
    uint4 dv = *(const uint4*)(identb + i);
    const unsigned short* ch = (const unsigned short*)&cv;
    const unsigned short* dh = (const unsigned short*)&dv;
    float sc = ss[o], sh = ss[cCOUT + o];
    float r[8];
#pragma unroll
    for (int j = 0; j < 8; ++j)
        r[j] = fmaf(bf16_f(ch[j]), sc, sh + bf16_f(dh[j]));
    *(float4*)(out + i)     = *(float4*)&r[0];
    *(float4*)(out + i + 4) = *(float4*)&r[4];
}

extern "C" void kernel_launch(void* const* d_in, const int* in_sizes, int n_in,
                              void* d_out, int out_size, void* d_ws, size_t ws_size,
                              hipStream_t stream) {
    const float* x      = (const float*)d_in[0];
    const int*   idx    = (const int*)d_in[1];
    const float* basis  = (const float*)d_in[2];
    const float* conv_w = (const float*)d_in[3];
    // d_in[4] = conv_b cancels under BN -> unused
    const float* pool_w = (const float*)d_in[5];
    const float* pool_b = (const float*)d_in[6];
    const float* gamma  = (const float*)d_in[7];
    const float* beta   = (const float*)d_in[8];
    float* out = (float*)d_out;

    char* wsb = (char*)d_ws;
    unsigned short* xt     = (unsigned short*)(wsb + OFF_XT);
    unsigned short* convb  = (unsigned short*)(wsb + OFF_CONVB);   // aliases xt (dead)
    unsigned short* identb = (unsigned short*)(wsb + OFF_IDENTB);  // aliases xt (dead)
    unsigned short* featA  = (unsigned short*)(wsb + OFF_FEATA);
    unsigned short* wB     = (unsigned short*)(wsb + OFF_WB);
    float*          ss     = (float*)(wsb + OFF_SS);
    float*          s1g    = (float*)(wsb + OFF_S1);
    float*          s2g    = (float*)(wsb + OFF_S2);

    k_tr   <<<dim3(cNIN / 128, cB), 256, 0, stream>>>(x, (unsigned*)xt);
    k_pack <<<(110592 + 255) / 256, 256, 0, stream>>>(conv_w, pool_w, wB);
    k_feat <<<4096, 192, 0, stream>>>(xt, idx, basis, featA);
    k_gemm <<<(cB * cNOUT) / 64, 256, 0, stream>>>(featA, wB, convb, identb, s1g, s2g);
    k_ss   <<<cCOUT, 256, 0, stream>>>(s1g, s2g, gamma, beta, pool_b, ss);
    k_final<<<(size_t)cB * cCOUT * cNOUT / 2048, 256, 0, stream>>>(convb, identb, ss, out);
}

// Round 14
// 129.333 us; speedup vs baseline: 6.9901x; 1.0433x over previous
//
#include <hip/hip_runtime.h>

typedef __attribute__((ext_vector_type(8))) short s16x8;
typedef __attribute__((ext_vector_type(4))) float f32x4;

constexpr int cB = 16, cCIN = 96, cCOUT = 192, cNIN = 16384, cNOUT = 4096;
constexpr float cEPS = 1e-5f;

// ws layout (bytes) — r9 verified
constexpr size_t OFF_XT     = 0;           // bf16 xt[b][j][c]  50,331,648 (dead after k_feat)
constexpr size_t OFF_CONVB  = 0;           // bf16 conv[b][o][n] 25,165,824 (aliases dead xt)
constexpr size_t OFF_IDENTB = 25165824;    // bf16 ident[b][o][n] 25,165,824 (aliases dead xt)
constexpr size_t OFF_FEATA  = 50331648;    // bf16 frag-order feat 75,497,472
constexpr size_t OFF_WB     = 125829120;   // bf16 frag-order W 221,184
constexpr size_t OFF_SS     = 126050304;   // fp32 scale/shift 1,536
constexpr size_t OFF_S1     = 126051840;   // fp32 partials1[o][2048] 1,572,864
constexpr size_t OFF_S2     = 127624704;   // fp32 partials2[o][2048] 1,572,864

__device__ inline unsigned bf16_rne(float f) {
    unsigned u = __builtin_bit_cast(unsigned, f);
    return (u + 0x7fffu + ((u >> 16) & 1u)) >> 16;
}
__device__ inline float bf16_f(unsigned short h) {
    unsigned u = ((unsigned)h) << 16;
    return __builtin_bit_cast(float, u);
}

// ---------- K1: transpose (blocks 0..2047) + weight pack (blocks 2048..2479) ----------
__launch_bounds__(256)
__global__ void k_trp(const float* __restrict__ x, unsigned* __restrict__ xto,
                      const float* __restrict__ cw, const float* __restrict__ pw,
                      unsigned short* __restrict__ wB) {
    __shared__ float s[96 * 133];
    const int blk = blockIdx.x, t = threadIdx.x;
    if (blk < 2048) {
        const int b = blk >> 7, j0 = (blk & 127) * 128;
        const float* xb = x + (size_t)b * 96 * 16384 + j0;
        for (int q = t; q < 3072; q += 256) {
            int c = q >> 5, j4 = (q & 31) * 4;
            float4 v = *(const float4*)(xb + (size_t)c * 16384 + j4);
            s[c * 133 + j4 + 0] = v.x;
            s[c * 133 + j4 + 1] = v.y;
            s[c * 133 + j4 + 2] = v.z;
            s[c * 133 + j4 + 3] = v.w;
        }
        __syncthreads();
        for (int q = t; q < 3072; q += 256) {
            int cp2 = q % 24, jj = q / 24;
            float f0 = s[(4 * cp2 + 0) * 133 + jj];
            float f1 = s[(4 * cp2 + 1) * 133 + jj];
            float f2 = s[(4 * cp2 + 2) * 133 + jj];
            float f3 = s[(4 * cp2 + 3) * 133 + jj];
            uint2 pr;
            pr.x = bf16_rne(f0) | (bf16_rne(f1) << 16);
            pr.y = bf16_rne(f2) | (bf16_rne(f3) << 16);
            *(uint2*)(xto + (size_t)(b * 16384 + j0 + jj) * 48 + cp2 * 2) = pr;
        }
    } else {
        int e = (blk - 2048) * 256 + t;
        if (e < 110592) {
            int r = e & 7, l = (e >> 3) & 63;
            int ts = e >> 9;
            int sI = ts % 18, ot = ts / 18;
            int o = ot * 16 + (l & 15);
            int ko = sI * 32 + ((l >> 4) << 3) + r;
            float v;
            if (ko < 480) { int m = ko / 96, c = ko % 96; v = cw[(o * 96 + c) * 5 + m]; }
            else          { int c = ko - 480;             v = pw[o * 96 + c]; }
            wB[e] = (unsigned short)bf16_rne(v);
        }
    }
}

// ---------- K2: gather + feat -> featA (A-frag order), XCD-swizzled (r9 verified) ----------
__launch_bounds__(192)
__global__ void k_feat(const unsigned short* __restrict__ xt,
                       const int* __restrict__ idx,
                       const float* __restrict__ basis,
                       unsigned short* __restrict__ featA) {
    __shared__ float s_bas[16 * 97];   // [nl][k*6+m]
    __shared__ int s_idx[256];         // [nl*16+kk]
    const int t = threadIdx.x;
    const int wg = blockIdx.x;
    const int xcd = wg & 7, slot = wg >> 3;
    const int b  = xcd * 2 + (slot >> 8);
    const int nt = slot & 255;
    const int n0 = nt * 16;

    for (int i = t; i < 256; i += 192)
        s_idx[i] = idx[n0 * 16 + i];
    for (int i = t; i < 16 * 96; i += 192) {
        int nl = i / 96, km = i % 96, k = km / 6, m = km % 6;
        float v = (m < 5) ? basis[((size_t)(n0 + nl) * 16 + k) * 5 + m] : 0.0625f;
        s_bas[nl * 97 + km] = v;
    }
    __syncthreads();

    const int c8 = t >> 4, nl = t & 15;
    float fm[6][8];
#pragma unroll
    for (int m = 0; m < 6; ++m)
#pragma unroll
        for (int j = 0; j < 8; ++j) fm[m][j] = 0.f;

    const size_t xbase = (size_t)b * 16384;
#pragma unroll 4
    for (int k = 0; k < 16; ++k) {
        int j = s_idx[nl * 16 + k];
        s16x8 v = *(const s16x8*)(xt + (xbase + j) * 96 + c8 * 8);
        float gf[8];
#pragma unroll
        for (int q = 0; q < 8; ++q) gf[q] = bf16_f((unsigned short)v[q]);
#pragma unroll
        for (int m = 0; m < 6; ++m) {
            float bv = s_bas[nl * 97 + k * 6 + m];
#pragma unroll
            for (int q = 0; q < 8; ++q) fm[m][q] = fmaf(gf[q], bv, fm[m][q]);
        }
    }

    const int tile = b * 256 + nt;
    const int fl = nl + ((c8 & 3) << 4);
#pragma unroll
    for (int m = 0; m < 6; ++m) {
        int s = 3 * m + (c8 >> 2);
        uint4 o;
        o.x = bf16_rne(fm[m][0]) | (bf16_rne(fm[m][1]) << 16);
        o.y = bf16_rne(fm[m][2]) | (bf16_rne(fm[m][3]) << 16);
        o.z = bf16_rne(fm[m][4]) | (bf16_rne(fm[m][5]) << 16);
        o.w = bf16_rne(fm[m][6]) | (bf16_rne(fm[m][7]) << 16);
        *(uint4*)(featA + ((size_t)(tile * 18 + s) * 64 + fl) * 8) = o;
    }
}

// ---------- K3: GEMM via MFMA; accI split out of main loop; prefetched A (r9 verified) ----------
__launch_bounds__(256, 3)
__global__ void k_gemm(const unsigned short* __restrict__ featA,
                       const unsigned short* __restrict__ wB,
                       unsigned short* __restrict__ convb,
                       unsigned short* __restrict__ identb,
                       float* __restrict__ s1g,
                       float* __restrict__ s2g) {
    __shared__ __align__(16) unsigned short s_c[192 * 72];  // [o][lr], pad 72
    const int t = threadIdx.x;
    const int w = t >> 6, lane = t & 63;
    const int wr = w & 1, wc = w >> 1;
    const int bid = blockIdx.x;
    const int tile0 = bid * 4 + wr * 2;
    const s16x8* A  = (const s16x8*)featA;
    const s16x8* Bw = (const s16x8*)wB;

    const f32x4 z = {0.f, 0.f, 0.f, 0.f};
    f32x4 accC[2][6];
#pragma unroll
    for (int rt = 0; rt < 2; ++rt)
#pragma unroll
        for (int j = 0; j < 6; ++j) accC[rt][j] = z;

    // ---- main loop: conv K-range s=0..14, software-prefetched A ----
    s16x8 a0 = A[(size_t)(tile0 * 18 + 0) * 64 + lane];
    s16x8 a1 = A[(size_t)((tile0 + 1) * 18 + 0) * 64 + lane];
    for (int s = 0; s < 15; ++s) {
        s16x8 na0 = A[(size_t)(tile0 * 18 + s + 1) * 64 + lane];
        s16x8 na1 = A[(size_t)((tile0 + 1) * 18 + s + 1) * 64 + lane];
#pragma unroll
        for (int j = 0; j < 6; ++j) {
            s16x8 bf = Bw[(size_t)((wc * 6 + j) * 18 + s) * 64 + lane];
            accC[0][j] = __builtin_amdgcn_mfma_f32_16x16x32_bf16(a0, bf, accC[0][j], 0, 0, 0);
            accC[1][j] = __builtin_amdgcn_mfma_f32_16x16x32_bf16(a1, bf, accC[1][j], 0, 0, 0);
        }
        a0 = na0; a1 = na1;
    }

    const int col_l = lane & 15, rg = (lane >> 4) * 4;
    const int b  = (bid * 64) >> 12;
    const int n0 = (bid * 64) & 4095;

    // ---- register-sourced BN partials (conv path only) ----
#pragma unroll
    for (int j = 0; j < 6; ++j) {
        float s1 = 0.f, s2 = 0.f;
#pragma unroll
        for (int rt = 0; rt < 2; ++rt)
#pragma unroll
            for (int r = 0; r < 4; ++r) {
                float v = accC[rt][j][r];
                s1 += v;
                s2 = fmaf(v, v, s2);
            }
        s1 += __shfl_xor(s1, 16); s2 += __shfl_xor(s2, 16);
        s1 += __shfl_xor(s1, 32); s2 += __shfl_xor(s2, 32);
        if (lane < 16) {
            int o = (wc * 6 + j) * 16 + lane;
            s1g[(size_t)o * 2048 + bid * 2 + wr] = s1;
            s2g[(size_t)o * 2048 + bid * 2 + wr] = s2;
        }
    }

    // ---- phase A: conv -> s_c -> global ----
#pragma unroll
    for (int rt = 0; rt < 2; ++rt) {
        int lr = (wr * 2 + rt) * 16 + rg;
#pragma unroll
        for (int j = 0; j < 6; ++j) {
            int o = (wc * 6 + j) * 16 + col_l;
#pragma unroll
            for (int r = 0; r < 4; ++r)
                s_c[o * 72 + lr + r] = (unsigned short)bf16_rne(accC[rt][j][r]);
        }
    }
    __syncthreads();
    for (int u = t; u < 1536; u += 256) {
        int o = u >> 3, part = u & 7;
        uint4 v = *(const uint4*)(&s_c[o * 72 + part * 8]);
        *(uint4*)(convb + ((size_t)(b * 192 + o)) * 4096 + n0 + part * 8) = v;
    }
    __syncthreads();

    // ---- identity tail: s=15..17 ----
    f32x4 accI[2][6];
#pragma unroll
    for (int rt = 0; rt < 2; ++rt)
#pragma unroll
        for (int j = 0; j < 6; ++j) accI[rt][j] = z;
#pragma unroll
    for (int s = 15; s < 18; ++s) {
        s16x8 b0 = A[(size_t)(tile0 * 18 + s) * 64 + lane];
        s16x8 b1 = A[(size_t)((tile0 + 1) * 18 + s) * 64 + lane];
#pragma unroll
        for (int j = 0; j < 6; ++j) {
            s16x8 bf = Bw[(size_t)((wc * 6 + j) * 18 + s) * 64 + lane];
            accI[0][j] = __builtin_amdgcn_mfma_f32_16x16x32_bf16(b0, bf, accI[0][j], 0, 0, 0);
            accI[1][j] = __builtin_amdgcn_mfma_f32_16x16x32_bf16(b1, bf, accI[1][j], 0, 0, 0);
        }
    }

    // ---- phase B: ident -> s_c -> global ----
#pragma unroll
    for (int rt = 0; rt < 2; ++rt) {
        int lr = (wr * 2 + rt) * 16 + rg;
#pragma unroll
        for (int j = 0; j < 6; ++j) {
            int o = (wc * 6 + j) * 16 + col_l;
#pragma unroll
            for (int r = 0; r < 4; ++r)
                s_c[o * 72 + lr + r] = (unsigned short)bf16_rne(accI[rt][j][r]);
        }
    }
    __syncthreads();
    for (int u = t; u < 1536; u += 256) {
        int o = u >> 3, part = u & 7;
        uint4 v = *(const uint4*)(&s_c[o * 72 + part * 8]);
        *(uint4*)(identb + ((size_t)(b * 192 + o)) * 4096 + n0 + part * 8) = v;
    }
}

// ---------- K4: reduce partials -> scale/shift (r9 verified) ----------
__launch_bounds__(256)
__global__ void k_ss(const float* __restrict__ s1g, const float* __restrict__ s2g,
                     const float* __restrict__ gamma, const float* __restrict__ beta,
                     const float* __restrict__ pool_b, float* __restrict__ ss) {
    int o = blockIdx.x, t = threadIdx.x;
    float s1 = 0.f, s2 = 0.f;
    for (int i = t; i < 2048; i += 256) {
        s1 += s1g[(size_t)o * 2048 + i];
        s2 += s2g[(size_t)o * 2048 + i];
    }
#pragma unroll
    for (int off = 32; off; off >>= 1) {
        s1 += __shfl_down(s1, off);
        s2 += __shfl_down(s2, off);
    }
    __shared__ float w1[4], w2[4];
    int lane = t & 63, wid = t >> 6;
    if (lane == 0) { w1[wid] = s1; w2[wid] = s2; }
    __syncthreads();
    if (t == 0) {
        float S1 = w1[0] + w1[1] + w1[2] + w1[3];
        float S2 = w2[0] + w2[1] + w2[2] + w2[3];
        float inv  = 1.0f / (cB * cNOUT);
        float mean = S1 * inv;
        float var  = S2 * inv - mean * mean;
        float scale = gamma[o] * rsqrtf(var + cEPS);
        ss[o]         = scale;
        ss[cCOUT + o] = beta[o] - mean * scale + pool_b[o];
    }
}

// ---------- K5: BN apply + residual (nontemporal out stores via ext-vector) ----------
__launch_bounds__(256)
__global__ void k_final(const unsigned short* __restrict__ convb,
                        const unsigned short* __restrict__ identb,
                        const float* __restrict__ ss,
                        float* __restrict__ out) {
    size_t i = ((size_t)blockIdx.x * 256 + threadIdx.x) * 8;
    int o = (int)((i >> 12) % cCOUT);
    uint4 cv = *(const uint4*)(convb + i);
    uint4 dv = *(const uint4*)(identb + i);
    const unsigned short* ch = (const unsigned short*)&cv;
    const unsigned short* dh = (const unsigned short*)&dv;
    float sc = ss[o], sh = ss[cCOUT + o];
    f32x4 r0, r1;
#pragma unroll
    for (int j = 0; j < 4; ++j)
        r0[j] = fmaf(bf16_f(ch[j]), sc, sh + bf16_f(dh[j]));
#pragma unroll
    for (int j = 0; j < 4; ++j)
        r1[j] = fmaf(bf16_f(ch[4 + j]), sc, sh + bf16_f(dh[4 + j]));
    __builtin_nontemporal_store(r0, (f32x4*)(out + i));
    __builtin_nontemporal_store(r1, (f32x4*)(out + i + 4));
}

extern "C" void kernel_launch(void* const* d_in, const int* in_sizes, int n_in,
                              void* d_out, int out_size, void* d_ws, size_t ws_size,
                              hipStream_t stream) {
    const float* x      = (const float*)d_in[0];
    const int*   idx    = (const int*)d_in[1];
    const float* basis  = (const float*)d_in[2];
    const float* conv_w = (const float*)d_in[3];
    // d_in[4] = conv_b cancels under BN -> unused
    const float* pool_w = (const float*)d_in[5];
    const float* pool_b = (const float*)d_in[6];
    const float* gamma  = (const float*)d_in[7];
    const float* beta   = (const float*)d_in[8];
    float* out = (float*)d_out;

    char* wsb = (char*)d_ws;
    unsigned short* xt     = (unsigned short*)(wsb + OFF_XT);
    unsigned short* convb  = (unsigned short*)(wsb + OFF_CONVB);   // aliases xt (dead)
    unsigned short* identb = (unsigned short*)(wsb + OFF_IDENTB);  // aliases xt (dead)
    unsigned short* featA  = (unsigned short*)(wsb + OFF_FEATA);
    unsigned short* wB     = (unsigned short*)(wsb + OFF_WB);
    float*          ss     = (float*)(wsb + OFF_SS);
    float*          s1g    = (float*)(wsb + OFF_S1);
    float*          s2g    = (float*)(wsb + OFF_S2);

    k_trp  <<<2048 + 432, 256, 0, stream>>>(x, (unsigned*)xt, conv_w, pool_w, wB);
    k_feat <<<4096, 192, 0, stream>>>(xt, idx, basis, featA);
    k_gemm <<<(cB * cNOUT) / 64, 256, 0, stream>>>(featA, wB, convb, identb, s1g, s2g);
    k_ss   <<<cCOUT, 256, 0, stream>>>(s1g, s2g, gamma, beta, pool_b, ss);
    k_final<<<(size_t)cB * cCOUT * cNOUT / 2048, 256, 0, stream>>>(convb, identb, ss, out);
}